// Round 10
// baseline (702.067 us; speedup 1.0000x reference)
//
#include <hip/hip_runtime.h>
#include <hip/hip_bf16.h>

// N=50000 nodes, F=64, H=2, E=800000.
// qk = x @ W_qk + b -> [N,H,2,F]; s[e,h] = <q[row],k[col]>; sparse softmax per row; mean heads.
// Softmax WITHOUT max subtraction (shift-invariant; |s| <~ 15, safe in fp32).
// R10: row-BUCKETED edge-parallel scores. Buckets of 128 rows (32KB q slice -> L1/L2-hot)
// halve the L3 random-request load (R8 analysis: L3 random path ~6 TB/s is the binding limit).
// Output written coalesced via perm[] indirection (R9 lesson: no scattered out writes;
// keep 4-edge MLP; CSR build kernels are cheap, serial row loops are not).
// R7 lesson: NO grid.sync. MFMA 16x16x32 bf16 layouts HW-verified.

#define NFEAT 64
#define NCOL  256   // 2*H*F
#define WT_STRIDE 72
#define BSHIFT 7    // 128 rows per bucket

typedef __attribute__((ext_vector_type(8))) short bf16x8;
typedef __attribute__((ext_vector_type(4))) float f32x4;

__device__ __forceinline__ unsigned short f2bf(float f) {
    union { __hip_bfloat16 h; unsigned short u; } cv;
    cv.h = __float2bfloat16(f);
    return cv.u;
}

__device__ __forceinline__ float dot_bf16x2(unsigned a, unsigned b) {
    float alo = __uint_as_float(a << 16), ahi = __uint_as_float(a & 0xFFFF0000u);
    float blo = __uint_as_float(b << 16), bhi = __uint_as_float(b & 0xFFFF0000u);
    return alo * blo + ahi * bhi;
}

// ---------------- Kernel 1: qk projection via MFMA (W transpose + den zero folded) ----------------
__global__ __launch_bounds__(256) void gemm_qk_mfma(
    const float* __restrict__ x, const float* __restrict__ W,
    const float* __restrict__ b,
    unsigned short* __restrict__ qo, unsigned short* __restrict__ ko,
    float* __restrict__ den, int N)
{
    __shared__ unsigned short WtL[NCOL * WT_STRIDE];
    __shared__ float bL[NCOL];
    const int tid = threadIdx.x;

    for (int i = tid; i < NFEAT * NCOL; i += 256) {
        const int kk = i >> 8, c = i & 255;
        WtL[c * WT_STRIDE + kk] = f2bf(W[i]);
    }
    bL[tid] = b[tid];

    const int t = blockIdx.x * 256 + tid;
    if (t < 2 * N) den[t] = 0.f;

    const int lane = tid & 63;
    const int wv   = tid >> 6;
    const int l15  = lane & 15;
    const int quad = lane >> 4;
    const int base = blockIdx.x * 128 + wv * 32;
    __syncthreads();

    if (base >= N) return;

    bf16x8 afrag[2][2];
#pragma unroll
    for (int s = 0; s < 2; ++s) {
        int m = base + s * 16 + l15;
        if (m >= N) m = N - 1;
        const float* xp = x + (size_t)m * NFEAT + quad * 8;
#pragma unroll
        for (int ks = 0; ks < 2; ++ks) {
            float4 a0 = *(const float4*)(xp + ks * 32);
            float4 a1 = *(const float4*)(xp + ks * 32 + 4);
            bf16x8 f;
            f[0] = f2bf(a0.x); f[1] = f2bf(a0.y); f[2] = f2bf(a0.z); f[3] = f2bf(a0.w);
            f[4] = f2bf(a1.x); f[5] = f2bf(a1.y); f[6] = f2bf(a1.z); f[7] = f2bf(a1.w);
            afrag[s][ks] = f;
        }
    }

#pragma unroll 4
    for (int ct = 0; ct < 16; ++ct) {
        const int c = ct * 16 + l15;
        bf16x8 b0 = *(const bf16x8*)(WtL + (size_t)c * WT_STRIDE + quad * 8);
        bf16x8 b1 = *(const bf16x8*)(WtL + (size_t)c * WT_STRIDE + 32 + quad * 8);
        const float bias = bL[c];
        const int h   = c >> 7;
        const int isk = (c >> 6) & 1;
        const int f0  = c & 63;
        unsigned short* dst = isk ? ko : qo;
#pragma unroll
        for (int s = 0; s < 2; ++s) {
            f32x4 acc = {0.f, 0.f, 0.f, 0.f};
            acc = __builtin_amdgcn_mfma_f32_16x16x32_bf16(afrag[s][0], b0, acc, 0, 0, 0);
            acc = __builtin_amdgcn_mfma_f32_16x16x32_bf16(afrag[s][1], b1, acc, 0, 0, 0);
#pragma unroll
            for (int r = 0; r < 4; ++r) {
                const int m = base + s * 16 + quad * 4 + r;
                if (m < N)
                    dst[(size_t)m * 128 + h * 64 + f0] = f2bf(acc[r] + bias);
            }
        }
    }
}

// ---------------- bucket build ----------------
__global__ __launch_bounds__(256) void hist_k(const int* __restrict__ ei,
                                              unsigned* __restrict__ cnt, int E) {
    const int e = blockIdx.x * 256 + threadIdx.x;
    if (e < E) atomicAdd(&cnt[((unsigned)ei[e]) >> BSHIFT], 1u);
}

// single-block exclusive scan, nb <= 512
__global__ __launch_bounds__(512) void scan_k(const unsigned* __restrict__ cnt,
                                              unsigned* __restrict__ bstart, int nb) {
    __shared__ unsigned wsum[8];
    const int t = threadIdx.x, lane = t & 63, wv = t >> 6;
    unsigned v = (t < nb) ? cnt[t] : 0u;
    unsigned inc = v;
    for (int off = 1; off < 64; off <<= 1) {
        unsigned u = __shfl_up(inc, off, 64);
        if (lane >= off) inc += u;
    }
    if (lane == 63) wsum[wv] = inc;
    __syncthreads();
    unsigned wbase = 0;
    for (int i = 0; i < wv; ++i) wbase += wsum[i];
    if (t < nb) bstart[t] = wbase + inc - v;
}

__global__ __launch_bounds__(256) void scat_k(const int* __restrict__ ei,
                                              const unsigned* __restrict__ bstart,
                                              unsigned* __restrict__ cursor,
                                              uint2* __restrict__ csr2,
                                              unsigned* __restrict__ perm, int E) {
    const int e = blockIdx.x * 256 + threadIdx.x;
    if (e >= E) return;
    const unsigned r = (unsigned)ei[e];
    const unsigned c = (unsigned)ei[E + e];
    const unsigned bkt = r >> BSHIFT;
    const unsigned p = bstart[bkt] + atomicAdd(&cursor[bkt], 1u);
    csr2[p] = make_uint2(r, c);
    perm[e] = p;
}

// ---------------- Kernel 2: bucketed scores -> exp -> segment-sum (4 edges / 16-lane group) ----------------
__global__ __launch_bounds__(256) void csr_scores(
    const unsigned short* __restrict__ q, const unsigned short* __restrict__ k,
    const uint2* __restrict__ csr2, float* __restrict__ exb,
    float* __restrict__ den, int E)
{
    const int grp  = (int)((blockIdx.x * 256 + threadIdx.x) >> 4);
    const int lane = threadIdx.x & 15;
    const int g0   = grp * 4;
    if (g0 >= E) return;

    unsigned v = 0;
    if (lane < 8 && g0 * 2 + lane < 2 * E)
        v = ((const unsigned*)csr2)[(size_t)g0 * 2 + lane];
    int rows[4], cols[4];
#pragma unroll
    for (int i = 0; i < 4; ++i) {
        rows[i] = __shfl((int)v, 2 * i, 16);
        cols[i] = __shfl((int)v, 2 * i + 1, 16);
    }

    const int nv = min(4, E - g0);
    uint4 qa[4], ka[4];
#pragma unroll
    for (int i = 0; i < 4; ++i) {
        if (i < nv) {
            qa[i] = ((const uint4*)(q + (size_t)rows[i] * 128))[lane];  // bucket-local: L1/L2-hot
            ka[i] = ((const uint4*)(k + (size_t)cols[i] * 128))[lane];  // random: L3
        }
    }

#pragma unroll
    for (int i = 0; i < 4; ++i) {
        if (i >= nv) break;
        float p = dot_bf16x2(qa[i].x, ka[i].x) + dot_bf16x2(qa[i].y, ka[i].y)
                + dot_bf16x2(qa[i].z, ka[i].z) + dot_bf16x2(qa[i].w, ka[i].w);
        p += __shfl_xor(p, 1);
        p += __shfl_xor(p, 2);
        p += __shfl_xor(p, 4);
        if ((lane & 7) == 0) {
            const int h  = lane >> 3;
            const float e = __expf(p);
            exb[(size_t)(g0 + i) * 2 + h] = e;
            atomicAdd(&den[(size_t)rows[i] * 2 + h], e);
        }
    }
}

// ---------------- Kernel 3: normalize, coalesced output via perm ----------------
__global__ __launch_bounds__(256) void out_k(
    const int* __restrict__ ei, const unsigned* __restrict__ perm,
    const float* __restrict__ exb, const float* __restrict__ den,
    float* __restrict__ out, int E)
{
    const int e = blockIdx.x * 256 + threadIdx.x;
    if (e >= E) return;
    const unsigned p = perm[e];
    const float2 ev = ((const float2*)exb)[p];          // L2-hot gather
    const int row = ei[e];
    const float2 dv = ((const float2*)den)[row];        // L2-hot gather
    out[e] = 0.5f * (ev.x / dv.x + ev.y / dv.y);        // coalesced write
}

extern "C" void kernel_launch(void* const* d_in, const int* in_sizes, int n_in,
                              void* d_out, int out_size, void* d_ws, size_t ws_size,
                              hipStream_t stream)
{
    const float* x   = (const float*)d_in[0];
    const float* W   = (const float*)d_in[1];
    const float* b   = (const float*)d_in[2];
    const int*   ei  = (const int*)d_in[3];
    float*       out = (float*)d_out;

    const int N = in_sizes[0] / NFEAT;     // 50000
    const int E = in_sizes[3] / 2;         // 800000
    const int NBUCK = (N + (1 << BSHIFT) - 1) >> BSHIFT;   // 391 (<=512 for scan_k)

    char* ws = (char*)d_ws;
    size_t off = 0;
    auto alloc = [&](size_t bytes) { void* p = ws + off; off += (bytes + 255) & ~(size_t)255; return p; };
    unsigned short* q_ws   = (unsigned short*)alloc((size_t)N * 128 * 2);   // 12.8 MB
    unsigned short* k_ws   = (unsigned short*)alloc((size_t)N * 128 * 2);   // 12.8 MB
    uint2*          csr2   = (uint2*)alloc((size_t)E * 8);                  // 6.4 MB
    float*          exb    = (float*)alloc((size_t)E * 2 * sizeof(float));  // 6.4 MB
    unsigned*       perm   = (unsigned*)alloc((size_t)E * 4);               // 3.2 MB
    float*          den_ws = (float*)alloc((size_t)N * 2 * sizeof(float));  // 0.4 MB
    unsigned*       cntcur = (unsigned*)alloc((size_t)1024 * 4);            // cnt[512]+cursor[512]
    unsigned*       bstart = (unsigned*)alloc((size_t)512 * 4);
    (void)ws_size;
    unsigned* cnt    = cntcur;
    unsigned* cursor = cntcur + 512;

    hipMemsetAsync(cntcur, 0, 1024 * 4, stream);

    gemm_qk_mfma<<<(N + 127) / 128, 256, 0, stream>>>(x, W, b, q_ws, k_ws, den_ws, N);
    hist_k<<<(E + 255) / 256, 256, 0, stream>>>(ei, cnt, E);
    scan_k<<<1, 512, 0, stream>>>(cnt, bstart, NBUCK);
    scat_k<<<(E + 255) / 256, 256, 0, stream>>>(ei, bstart, cursor, csr2, perm, E);
    csr_scores<<<((size_t)(E + 3) / 4 * 16 + 255) / 256, 256, 0, stream>>>(q_ws, k_ws, csr2, exb, den_ws, E);
    out_k<<<(E + 255) / 256, 256, 0, stream>>>(ei, perm, exb, den_ws, out, E);
}

// Round 11
// 215.580 us; speedup vs baseline: 3.2566x; 3.2566x over previous
//
#include <hip/hip_runtime.h>
#include <hip/hip_bf16.h>

// N=50000 nodes, F=64, H=2, E=800000.
// qk = x @ W_qk + b -> [N,H,2,F]; s[e,h] = <q[row],k[col]>; sparse softmax per row; mean heads.
// Softmax WITHOUT max subtraction (shift-invariant; |s| <~ 15, safe in fp32).
// R11 = R9's per-row CSR build (cheap, contention depth ~16) + R10's edge-parallel
// 4-edge consumption on row-sorted edges (q-gathers L1-local) + perm-indirect coalesced out.
// R10 lesson: NEVER funnel E atomics into few addresses (391-bucket cursor = 281us).
// R9 lesson: no serial per-row loops; R7 lesson: no grid.sync. MFMA layouts HW-verified.

#define NFEAT 64
#define NCOL  256   // 2*H*F
#define WT_STRIDE 72

typedef __attribute__((ext_vector_type(8))) short bf16x8;
typedef __attribute__((ext_vector_type(4))) float f32x4;

__device__ __forceinline__ unsigned short f2bf(float f) {
    union { __hip_bfloat16 h; unsigned short u; } cv;
    cv.h = __float2bfloat16(f);
    return cv.u;
}

__device__ __forceinline__ float dot_bf16x2(unsigned a, unsigned b) {
    float alo = __uint_as_float(a << 16), ahi = __uint_as_float(a & 0xFFFF0000u);
    float blo = __uint_as_float(b << 16), bhi = __uint_as_float(b & 0xFFFF0000u);
    return alo * blo + ahi * bhi;
}

// ---------------- Kernel 1: qk projection via MFMA (W transpose + den zero folded) ----------------
__global__ __launch_bounds__(256) void gemm_qk_mfma(
    const float* __restrict__ x, const float* __restrict__ W,
    const float* __restrict__ b,
    unsigned short* __restrict__ qo, unsigned short* __restrict__ ko,
    float* __restrict__ den, int N)
{
    __shared__ unsigned short WtL[NCOL * WT_STRIDE];
    __shared__ float bL[NCOL];
    const int tid = threadIdx.x;

    for (int i = tid; i < NFEAT * NCOL; i += 256) {
        const int kk = i >> 8, c = i & 255;
        WtL[c * WT_STRIDE + kk] = f2bf(W[i]);
    }
    bL[tid] = b[tid];

    const int t = blockIdx.x * 256 + tid;
    if (t < 2 * N) den[t] = 0.f;

    const int lane = tid & 63;
    const int wv   = tid >> 6;
    const int l15  = lane & 15;
    const int quad = lane >> 4;
    const int base = blockIdx.x * 128 + wv * 32;
    __syncthreads();

    if (base >= N) return;

    bf16x8 afrag[2][2];
#pragma unroll
    for (int s = 0; s < 2; ++s) {
        int m = base + s * 16 + l15;
        if (m >= N) m = N - 1;
        const float* xp = x + (size_t)m * NFEAT + quad * 8;
#pragma unroll
        for (int ks = 0; ks < 2; ++ks) {
            float4 a0 = *(const float4*)(xp + ks * 32);
            float4 a1 = *(const float4*)(xp + ks * 32 + 4);
            bf16x8 f;
            f[0] = f2bf(a0.x); f[1] = f2bf(a0.y); f[2] = f2bf(a0.z); f[3] = f2bf(a0.w);
            f[4] = f2bf(a1.x); f[5] = f2bf(a1.y); f[6] = f2bf(a1.z); f[7] = f2bf(a1.w);
            afrag[s][ks] = f;
        }
    }

#pragma unroll 4
    for (int ct = 0; ct < 16; ++ct) {
        const int c = ct * 16 + l15;
        bf16x8 b0 = *(const bf16x8*)(WtL + (size_t)c * WT_STRIDE + quad * 8);
        bf16x8 b1 = *(const bf16x8*)(WtL + (size_t)c * WT_STRIDE + 32 + quad * 8);
        const float bias = bL[c];
        const int h   = c >> 7;
        const int isk = (c >> 6) & 1;
        const int f0  = c & 63;
        unsigned short* dst = isk ? ko : qo;
#pragma unroll
        for (int s = 0; s < 2; ++s) {
            f32x4 acc = {0.f, 0.f, 0.f, 0.f};
            acc = __builtin_amdgcn_mfma_f32_16x16x32_bf16(afrag[s][0], b0, acc, 0, 0, 0);
            acc = __builtin_amdgcn_mfma_f32_16x16x32_bf16(afrag[s][1], b1, acc, 0, 0, 0);
#pragma unroll
            for (int r = 0; r < 4; ++r) {
                const int m = base + s * 16 + quad * 4 + r;
                if (m < N)
                    dst[(size_t)m * 128 + h * 64 + f0] = f2bf(acc[r] + bias);
            }
        }
    }
}

// ---------------- CSR build (per-row cursors: contention depth ~ degree ~ 16) ----------------
__global__ __launch_bounds__(256) void hist_k(const int* __restrict__ ei,
                                              unsigned* __restrict__ cnt, int E) {
    const int e = blockIdx.x * 256 + threadIdx.x;
    if (e < E) atomicAdd(&cnt[ei[e]], 1u);
}

// exclusive scan within 256-blocks; block totals to bsum
__global__ __launch_bounds__(256) void scan_a(const unsigned* __restrict__ cnt,
                                              unsigned* __restrict__ rsl,
                                              unsigned* __restrict__ bsum, int n) {
    __shared__ unsigned wsum[4];
    const int idx  = blockIdx.x * 256 + threadIdx.x;
    const int lane = threadIdx.x & 63;
    const int wv   = threadIdx.x >> 6;
    unsigned v = (idx < n) ? cnt[idx] : 0u;
    unsigned inc = v;
    for (int off = 1; off < 64; off <<= 1) {
        unsigned t = __shfl_up(inc, off, 64);
        if (lane >= off) inc += t;
    }
    if (lane == 63) wsum[wv] = inc;
    __syncthreads();
    unsigned wbase = 0;
    for (int i = 0; i < wv; ++i) wbase += wsum[i];
    if (idx < n) rsl[idx] = wbase + inc - v;
    if (threadIdx.x == 255) bsum[blockIdx.x] = wbase + inc;
}

// exclusive scan of bsum[0..nb-1] (nb <= 256), one block
__global__ __launch_bounds__(256) void scan_b(const unsigned* __restrict__ bsum,
                                              unsigned* __restrict__ bpre, int nb) {
    __shared__ unsigned wsum[4];
    const int t    = threadIdx.x;
    const int lane = t & 63;
    const int wv   = t >> 6;
    unsigned v = (t < nb) ? bsum[t] : 0u;
    unsigned inc = v;
    for (int off = 1; off < 64; off <<= 1) {
        unsigned u = __shfl_up(inc, off, 64);
        if (lane >= off) inc += u;
    }
    if (lane == 63) wsum[wv] = inc;
    __syncthreads();
    unsigned wbase = 0;
    for (int i = 0; i < wv; ++i) wbase += wsum[i];
    bpre[t] = wbase + inc - v;
}

__global__ __launch_bounds__(256) void scat_k(const int* __restrict__ ei,
                                              const unsigned* __restrict__ rsl,
                                              const unsigned* __restrict__ bpre,
                                              unsigned* __restrict__ cursor,
                                              uint2* __restrict__ csr2,
                                              unsigned* __restrict__ perm, int E) {
    const int e = blockIdx.x * 256 + threadIdx.x;
    if (e >= E) return;
    const unsigned r = (unsigned)ei[e];
    const unsigned base = rsl[r] + bpre[r >> 8];
    const unsigned p = base + atomicAdd(&cursor[r], 1u);
    csr2[p] = make_uint2(r, (unsigned)ei[E + e]);   // {row, col} sorted by row
    perm[e] = p;                                     // coalesced write
}

// ---------------- Kernel 2: sorted scores -> exp -> segment-sum (4 edges / 16-lane group) ----------------
// Rows within a group are usually identical (sorted) -> q-gathers L1-hit; den atomics
// flushed on row change (~4x fewer atomics).
__global__ __launch_bounds__(256) void csr_scores(
    const unsigned short* __restrict__ q, const unsigned short* __restrict__ k,
    const uint2* __restrict__ csr2, float* __restrict__ exb,
    float* __restrict__ den, int E)
{
    const int grp  = (int)((blockIdx.x * 256 + threadIdx.x) >> 4);
    const int lane = threadIdx.x & 15;
    const int g0   = grp * 4;
    if (g0 >= E) return;

    unsigned v = 0;
    if (lane < 8 && g0 * 2 + lane < 2 * E)
        v = ((const unsigned*)csr2)[(size_t)g0 * 2 + lane];
    int rows[4], cols[4];
#pragma unroll
    for (int i = 0; i < 4; ++i) {
        rows[i] = __shfl((int)v, 2 * i, 16);
        cols[i] = __shfl((int)v, 2 * i + 1, 16);
    }

    const int nv = min(4, E - g0);
    uint4 qa[4], ka[4];
#pragma unroll
    for (int i = 0; i < 4; ++i) {
        if (i < nv) {
            qa[i] = ((const uint4*)(q + (size_t)rows[i] * 128))[lane];  // row-sorted: L1-hot
            ka[i] = ((const uint4*)(k + (size_t)cols[i] * 128))[lane];  // random: L3
        }
    }

    float pv[4];
#pragma unroll
    for (int i = 0; i < 4; ++i) {
        float p = 0.f;
        if (i < nv)
            p = dot_bf16x2(qa[i].x, ka[i].x) + dot_bf16x2(qa[i].y, ka[i].y)
              + dot_bf16x2(qa[i].z, ka[i].z) + dot_bf16x2(qa[i].w, ka[i].w);
        p += __shfl_xor(p, 1);
        p += __shfl_xor(p, 2);
        p += __shfl_xor(p, 4);
        pv[i] = p;
    }

    if ((lane & 7) == 0) {
        const int h = lane >> 3;
        float accs = 0.f;
#pragma unroll
        for (int i = 0; i < 4; ++i) {
            if (i < nv) {
                const float e = __expf(pv[i]);
                exb[(size_t)(g0 + i) * 2 + h] = e;
                accs += e;
                const bool flush = (i + 1 >= nv) || (rows[i + 1] != rows[i]);
                if (flush) {
                    atomicAdd(&den[(size_t)rows[i] * 2 + h], accs);
                    accs = 0.f;
                }
            }
        }
    }
}

// ---------------- Kernel 3: normalize, coalesced output via perm ----------------
__global__ __launch_bounds__(256) void out_k(
    const int* __restrict__ ei, const unsigned* __restrict__ perm,
    const float* __restrict__ exb, const float* __restrict__ den,
    float* __restrict__ out, int E)
{
    const int e = blockIdx.x * 256 + threadIdx.x;
    if (e >= E) return;
    const unsigned p = perm[e];
    const float2 ev = ((const float2*)exb)[p];          // L2-hot gather
    const int row = ei[e];
    const float2 dv = ((const float2*)den)[row];        // L2-hot gather
    out[e] = 0.5f * (ev.x / dv.x + ev.y / dv.y);        // coalesced write
}

extern "C" void kernel_launch(void* const* d_in, const int* in_sizes, int n_in,
                              void* d_out, int out_size, void* d_ws, size_t ws_size,
                              hipStream_t stream)
{
    const float* x   = (const float*)d_in[0];
    const float* W   = (const float*)d_in[1];
    const float* b   = (const float*)d_in[2];
    const int*   ei  = (const int*)d_in[3];
    float*       out = (float*)d_out;

    const int N = in_sizes[0] / NFEAT;     // 50000
    const int E = in_sizes[3] / 2;         // 800000
    const int NB = (N + 1 + 255) / 256;    // scan blocks over cnt[0..N]

    char* ws = (char*)d_ws;
    size_t off = 0;
    auto alloc = [&](size_t bytes) { void* p = ws + off; off += (bytes + 255) & ~(size_t)255; return p; };
    unsigned short* q_ws   = (unsigned short*)alloc((size_t)N * 128 * 2);   // 12.8 MB
    unsigned short* k_ws   = (unsigned short*)alloc((size_t)N * 128 * 2);   // 12.8 MB
    uint2*          csr2   = (uint2*)alloc((size_t)E * 8);                  // 6.4 MB
    float*          exb    = (float*)alloc((size_t)E * 2 * sizeof(float));  // 6.4 MB
    unsigned*       perm   = (unsigned*)alloc((size_t)E * 4);               // 3.2 MB
    float*          den_ws = (float*)alloc((size_t)N * 2 * sizeof(float));  // 0.4 MB
    unsigned*       cnt    = (unsigned*)alloc((size_t)(N + 1) * 4);
    unsigned*       cursor = (unsigned*)alloc((size_t)N * 4);
    unsigned*       rsl    = (unsigned*)alloc((size_t)(N + 1) * 4);
    unsigned*       bsum   = (unsigned*)alloc((size_t)NB * 4);
    unsigned*       bpre   = (unsigned*)alloc((size_t)256 * 4);
    (void)ws_size;

    // zero cnt[0..N] + cursor[0..N-1] (adjacent allocations -> one memset)
    size_t zbytes = (size_t)((char*)(cursor + N) - (char*)cnt);
    hipMemsetAsync(cnt, 0, zbytes, stream);

    gemm_qk_mfma<<<(N + 127) / 128, 256, 0, stream>>>(x, W, b, q_ws, k_ws, den_ws, N);
    hist_k<<<(E + 255) / 256, 256, 0, stream>>>(ei, cnt, E);
    scan_a<<<NB, 256, 0, stream>>>(cnt, rsl, bsum, N + 1);
    scan_b<<<1, 256, 0, stream>>>(bsum, bpre, NB);
    scat_k<<<(E + 255) / 256, 256, 0, stream>>>(ei, rsl, bpre, cursor, csr2, perm, E);
    csr_scores<<<((size_t)(E + 3) / 4 * 16 + 255) / 256, 256, 0, stream>>>(q_ws, k_ws, csr2, exb, den_ws, E);
    out_k<<<(E + 255) / 256, 256, 0, stream>>>(ei, perm, exb, den_ws, out, E);
}

// Round 12
// 151.307 us; speedup vs baseline: 4.6400x; 1.4248x over previous
//
#include <hip/hip_runtime.h>
#include <hip/hip_bf16.h>

// N=50000 nodes, F=64, H=2, E=800000.
// qk = x @ W_qk + b -> [N,H,2,F]; s[e,h] = <q[row],k[col]>; sparse softmax per row; mean heads.
// Softmax WITHOUT max subtraction (shift-invariant; |s| <~ 15, safe in fp32).
// R12: XCD-affine col-sharding. Edges partitioned into 8 shards by col range (contiguous
// 6250-node ranges -> no L2 set aliasing); scores block j serves shard j&7 so each XCD
// (blockIdx%8 round-robin heuristic) keeps its 3.2MB k-slice L2-resident. q loaded
// nontemporal to avoid thrashing the k shard. Partition is deterministic LDS-histogram
// radix (R10 lesson: no few-address global atomics; R11 lesson: no random fine-grain
// global writes - scatter goes to 8 ADVANCING streams per block). out via perm gather.
// R7 lesson: no grid.sync. MFMA 16x16x32 bf16 layouts HW-verified.
// NOTE: packs row/col into 16 bits each (requires N <= 65536; here N=50000).

#define NFEAT 64
#define NCOL  256   // 2*H*F
#define WT_STRIDE 72
#define CHUNK 2048  // edges per partition block

typedef __attribute__((ext_vector_type(8))) short bf16x8;
typedef __attribute__((ext_vector_type(4))) float f32x4;
typedef __attribute__((ext_vector_type(4))) unsigned int u32x4;

__device__ __forceinline__ unsigned short f2bf(float f) {
    union { __hip_bfloat16 h; unsigned short u; } cv;
    cv.h = __float2bfloat16(f);
    return cv.u;
}

__device__ __forceinline__ float dot_bf16x2(unsigned a, unsigned b) {
    float alo = __uint_as_float(a << 16), ahi = __uint_as_float(a & 0xFFFF0000u);
    float blo = __uint_as_float(b << 16), bhi = __uint_as_float(b & 0xFFFF0000u);
    return alo * blo + ahi * bhi;
}

// ---------------- Kernel 1: qk projection via MFMA (W transpose + den zero folded) ----------------
__global__ __launch_bounds__(256) void gemm_qk_mfma(
    const float* __restrict__ x, const float* __restrict__ W,
    const float* __restrict__ b,
    unsigned short* __restrict__ qo, unsigned short* __restrict__ ko,
    float* __restrict__ den, int N)
{
    __shared__ unsigned short WtL[NCOL * WT_STRIDE];
    __shared__ float bL[NCOL];
    const int tid = threadIdx.x;

    for (int i = tid; i < NFEAT * NCOL; i += 256) {
        const int kk = i >> 8, c = i & 255;
        WtL[c * WT_STRIDE + kk] = f2bf(W[i]);
    }
    bL[tid] = b[tid];

    const int t = blockIdx.x * 256 + tid;
    if (t < 2 * N) den[t] = 0.f;

    const int lane = tid & 63;
    const int wv   = tid >> 6;
    const int l15  = lane & 15;
    const int quad = lane >> 4;
    const int base = blockIdx.x * 128 + wv * 32;
    __syncthreads();

    if (base >= N) return;

    bf16x8 afrag[2][2];
#pragma unroll
    for (int s = 0; s < 2; ++s) {
        int m = base + s * 16 + l15;
        if (m >= N) m = N - 1;
        const float* xp = x + (size_t)m * NFEAT + quad * 8;
#pragma unroll
        for (int ks = 0; ks < 2; ++ks) {
            float4 a0 = *(const float4*)(xp + ks * 32);
            float4 a1 = *(const float4*)(xp + ks * 32 + 4);
            bf16x8 f;
            f[0] = f2bf(a0.x); f[1] = f2bf(a0.y); f[2] = f2bf(a0.z); f[3] = f2bf(a0.w);
            f[4] = f2bf(a1.x); f[5] = f2bf(a1.y); f[6] = f2bf(a1.z); f[7] = f2bf(a1.w);
            afrag[s][ks] = f;
        }
    }

#pragma unroll 4
    for (int ct = 0; ct < 16; ++ct) {
        const int c = ct * 16 + l15;
        bf16x8 b0 = *(const bf16x8*)(WtL + (size_t)c * WT_STRIDE + quad * 8);
        bf16x8 b1 = *(const bf16x8*)(WtL + (size_t)c * WT_STRIDE + 32 + quad * 8);
        const float bias = bL[c];
        const int h   = c >> 7;
        const int isk = (c >> 6) & 1;
        const int f0  = c & 63;
        unsigned short* dst = isk ? ko : qo;
#pragma unroll
        for (int s = 0; s < 2; ++s) {
            f32x4 acc = {0.f, 0.f, 0.f, 0.f};
            acc = __builtin_amdgcn_mfma_f32_16x16x32_bf16(afrag[s][0], b0, acc, 0, 0, 0);
            acc = __builtin_amdgcn_mfma_f32_16x16x32_bf16(afrag[s][1], b1, acc, 0, 0, 0);
#pragma unroll
            for (int r = 0; r < 4; ++r) {
                const int m = base + s * 16 + quad * 4 + r;
                if (m < N)
                    dst[(size_t)m * 128 + h * 64 + f0] = f2bf(acc[r] + bias);
            }
        }
    }
}

// ---------------- Partition pass 1: per-block shard histogram (LDS, no global atomics) ----------------
__global__ __launch_bounds__(256) void hist8(const int* __restrict__ ei,
                                             unsigned* __restrict__ cnt, // [8][B1] shard-major
                                             int E, int B1, int SH) {
    __shared__ unsigned c8[8];
    const int tid = threadIdx.x;
    if (tid < 8) c8[tid] = 0;
    __syncthreads();
    const int e0 = blockIdx.x * CHUNK;
#pragma unroll
    for (int it = 0; it < CHUNK / 256; ++it) {
        const int e = e0 + it * 256 + tid;
        if (e < E) {
            const unsigned col = (unsigned)ei[E + e];
            const unsigned s = min(col / (unsigned)SH, 7u);
            atomicAdd(&c8[s], 1u);
        }
    }
    __syncthreads();
    if (tid < 8) cnt[tid * B1 + blockIdx.x] = c8[tid];
}

// ---------------- Partition pass 2: exclusive scan of cnt[0..total) (one block) ----------------
__global__ __launch_bounds__(1024) void scan8(const unsigned* __restrict__ cnt,
                                              unsigned* __restrict__ off, int total) {
    __shared__ unsigned wsum[16];
    const int t = threadIdx.x, lane = t & 63, wv = t >> 6;
    const int per = (total + 1023) >> 10;
    const int i0 = t * per;
    unsigned s = 0;
    for (int i = 0; i < per; ++i) { int idx = i0 + i; if (idx < total) s += cnt[idx]; }
    unsigned inc = s;
    for (int o = 1; o < 64; o <<= 1) {
        unsigned u = __shfl_up(inc, o, 64);
        if (lane >= o) inc += u;
    }
    if (lane == 63) wsum[wv] = inc;
    __syncthreads();
    unsigned wbase = 0;
    for (int w = 0; w < wv; ++w) wbase += wsum[w];
    unsigned run = wbase + inc - s;
    for (int i = 0; i < per; ++i) {
        int idx = i0 + i;
        if (idx < total) { unsigned v = cnt[idx]; off[idx] = run; run += v; }
    }
}

// ---------------- Partition pass 3: scatter into 8 advancing streams per block ----------------
__global__ __launch_bounds__(256) void scat8(const int* __restrict__ ei,
                                             const unsigned* __restrict__ off, // [8][B1]
                                             unsigned* __restrict__ csr1,      // packed row<<16|col
                                             unsigned* __restrict__ perm,      // perm[eid] = pos
                                             int E, int B1, int SH) {
    __shared__ unsigned base8[8];
    __shared__ unsigned cur8[8];
    const int tid = threadIdx.x;
    if (tid < 8) { base8[tid] = off[tid * B1 + blockIdx.x]; cur8[tid] = 0; }
    __syncthreads();
    const int e0 = blockIdx.x * CHUNK;
#pragma unroll
    for (int it = 0; it < CHUNK / 256; ++it) {
        const int e = e0 + it * 256 + tid;
        if (e < E) {
            const unsigned row = (unsigned)ei[e];
            const unsigned col = (unsigned)ei[E + e];
            const unsigned s = min(col / (unsigned)SH, 7u);
            const unsigned pos = base8[s] + atomicAdd(&cur8[s], 1u);
            csr1[pos] = (row << 16) | col;   // 8 advancing streams (write-combine friendly)
            perm[e] = pos;                   // coalesced
        }
    }
}

// ---------------- Kernel 2: sharded scores -> exp -> segment-sum ----------------
// Block j serves shard j&7 (XCD-affine); 16 lanes/edge, 4 edges/group; grid-strides
// over 64-edge slices of its shard. q loads nontemporal (protect k-shard residency).
__global__ __launch_bounds__(256) void scores_sh(
    const unsigned short* __restrict__ q, const unsigned short* __restrict__ k,
    const unsigned* __restrict__ csr1, const unsigned* __restrict__ off,
    float* __restrict__ exb, float* __restrict__ den, int E, int B1)
{
    const int s      = blockIdx.x & 7;
    const int nslice = gridDim.x >> 3;
    const unsigned start = off[s * B1];
    const unsigned end   = (s == 7) ? (unsigned)E : off[(s + 1) * B1];
    const int tid    = threadIdx.x;
    const int lane   = tid & 15;
    const int grpIdx = tid >> 4;   // 0..15

    for (unsigned sl = (unsigned)(blockIdx.x >> 3); start + sl * 64u < end; sl += (unsigned)nslice) {
        const unsigned p0 = start + sl * 64u + (unsigned)grpIdx * 4u;
        if (p0 >= end) continue;
        const int nv = min(4, (int)(end - p0));

        unsigned rc = 0;
        if (lane < nv) rc = csr1[p0 + lane];
        int rows[4], cols[4];
#pragma unroll
        for (int i = 0; i < 4; ++i) {
            const unsigned v = (unsigned)__shfl((int)rc, i, 16);
            rows[i] = (int)(v >> 16);
            cols[i] = (int)(v & 0xFFFFu);
        }

        u32x4 qa[4], ka[4];
#pragma unroll
        for (int i = 0; i < 4; ++i) {
            if (i < nv) {
                qa[i] = __builtin_nontemporal_load(((const u32x4*)(q + (size_t)rows[i] * 128)) + lane);
                ka[i] = ((const u32x4*)(k + (size_t)cols[i] * 128))[lane];  // XCD-L2-resident shard
            }
        }

#pragma unroll
        for (int i = 0; i < 4; ++i) {
            if (i >= nv) break;
            float p = dot_bf16x2(qa[i][0], ka[i][0]) + dot_bf16x2(qa[i][1], ka[i][1])
                    + dot_bf16x2(qa[i][2], ka[i][2]) + dot_bf16x2(qa[i][3], ka[i][3]);
            p += __shfl_xor(p, 1);
            p += __shfl_xor(p, 2);
            p += __shfl_xor(p, 4);
            if ((lane & 7) == 0) {
                const int h  = lane >> 3;
                const float e = __expf(p);
                exb[(size_t)(p0 + i) * 2 + h] = e;   // coalesced-ish (32B/group)
                atomicAdd(&den[(size_t)rows[i] * 2 + h], e);
            }
        }
    }
}

// ---------------- Kernel 3: normalize, coalesced output via perm gather ----------------
__global__ __launch_bounds__(256) void out_k(
    const int* __restrict__ ei, const unsigned* __restrict__ perm,
    const float* __restrict__ exb, const float* __restrict__ den,
    float* __restrict__ out, int E)
{
    const int e = blockIdx.x * 256 + threadIdx.x;
    if (e >= E) return;
    const unsigned p = perm[e];                      // coalesced
    const float2 ev = ((const float2*)exb)[p];       // L2/L3 gather (6.4 MB)
    const int row = ei[e];
    const float2 dv = ((const float2*)den)[row];     // L2-hot
    out[e] = 0.5f * (ev.x / dv.x + ev.y / dv.y);     // coalesced write
}

extern "C" void kernel_launch(void* const* d_in, const int* in_sizes, int n_in,
                              void* d_out, int out_size, void* d_ws, size_t ws_size,
                              hipStream_t stream)
{
    const float* x   = (const float*)d_in[0];
    const float* W   = (const float*)d_in[1];
    const float* b   = (const float*)d_in[2];
    const int*   ei  = (const int*)d_in[3];
    float*       out = (float*)d_out;

    const int N  = in_sizes[0] / NFEAT;           // 50000
    const int E  = in_sizes[3] / 2;               // 800000
    const int B1 = (E + CHUNK - 1) / CHUNK;       // 391
    const int SH = (N + 7) / 8;                   // 6250 (contiguous col shards)

    char* ws = (char*)d_ws;
    size_t woff = 0;
    auto alloc = [&](size_t bytes) { void* p = ws + woff; woff += (bytes + 255) & ~(size_t)255; return p; };
    unsigned short* q_ws   = (unsigned short*)alloc((size_t)N * 128 * 2);   // 12.8 MB
    unsigned short* k_ws   = (unsigned short*)alloc((size_t)N * 128 * 2);   // 12.8 MB
    float*          exb    = (float*)alloc((size_t)E * 2 * sizeof(float));  // 6.4 MB
    unsigned*       perm   = (unsigned*)alloc((size_t)E * 4);               // 3.2 MB
    unsigned*       csr1   = (unsigned*)alloc((size_t)E * 4);               // 3.2 MB
    float*          den_ws = (float*)alloc((size_t)N * 2 * sizeof(float));  // 0.4 MB
    unsigned*       cnt    = (unsigned*)alloc((size_t)8 * B1 * 4);
    unsigned*       off    = (unsigned*)alloc((size_t)8 * B1 * 4);
    (void)ws_size;

    gemm_qk_mfma<<<(N + 127) / 128, 256, 0, stream>>>(x, W, b, q_ws, k_ws, den_ws, N);
    hist8<<<B1, 256, 0, stream>>>(ei, cnt, E, B1, SH);
    scan8<<<1, 1024, 0, stream>>>(cnt, off, 8 * B1);
    scat8<<<B1, 256, 0, stream>>>(ei, off, csr1, perm, E, B1, SH);
    scores_sh<<<12800, 256, 0, stream>>>(q_ws, k_ws, csr1, off, exb, den_ws, E, B1);
    out_k<<<(E + 255) / 256, 256, 0, stream>>>(ei, perm, exb, den_ws, out, E);
}

// Round 13
// 142.393 us; speedup vs baseline: 4.9305x; 1.0626x over previous
//
#include <hip/hip_runtime.h>
#include <hip/hip_bf16.h>

// N=50000 nodes, F=64, H=2, E=800000.
// qk = x @ W_qk + b -> [N,H,2,F]; s[e,h] = <q[row],k[col]>; sparse softmax per row; mean heads.
// Softmax WITHOUT max subtraction (shift-invariant; |s| <~ 15, safe in fp32).
// FINAL (R8 structure): 3 kernels: [gemm(+W-transpose+den-zero)] -> [scores+exp+segsum] -> [normalize].
//
// Ceiling analysis (R6/R8/R11/R12 evidence): the scores kernel issues 6.4M random 64B
// line-requests (4 q-lines + 4 k-lines per edge); MI355X services random requests at
// ~6 lines/cy/XCD (~48/cy device) REGARDLESS of L2/L3 hit level -> ~55us floor; measured
// 59.5us. Reordering (CSR/sort/shard, R9-R12) cuts requests to ~3.6M but build+perm
// mechanics cost >= the savings (random cross-XCD scatters, perm gather). Harness
// restore/poison floor ~55-60us is invariant. R7 lesson: no grid.sync (cg barrier
// ~190us/sync). R10 lesson: no few-address global atomics. R11 lesson: no random
// fine-grain global writes. MFMA 16x16x32 bf16 layouts HW-verified (m89/m91).

#define NFEAT 64
#define NCOL  256   // 2*H*F
#define WT_STRIDE 72  // shorts; 144B row stride: 16B-aligned

typedef __attribute__((ext_vector_type(8))) short bf16x8;
typedef __attribute__((ext_vector_type(4))) float f32x4;

__device__ __forceinline__ unsigned short f2bf(float f) {
    union { __hip_bfloat16 h; unsigned short u; } cv;
    cv.h = __float2bfloat16(f);
    return cv.u;
}

__device__ __forceinline__ float dot_bf16x2(unsigned a, unsigned b) {
    float alo = __uint_as_float(a << 16), ahi = __uint_as_float(a & 0xFFFF0000u);
    float blo = __uint_as_float(b << 16), bhi = __uint_as_float(b & 0xFFFF0000u);
    return alo * blo + ahi * bhi;
}

// ---------------- Kernel 1: qk projection via MFMA (W transpose + den zero folded) ----------------
// Block: 256 thr = 4 waves; each wave 32 rows (2 stripes x 16) x 256 cols.
// W[k][c] fp32 read coalesced, converted + transposed into LDS WtL[c][k] bf16 (stride 72).
// Output bf16 layout: q[n*128 + h*64 + f] (256B contiguous per node).
__global__ __launch_bounds__(256) void gemm_qk_mfma(
    const float* __restrict__ x, const float* __restrict__ W,
    const float* __restrict__ b,
    unsigned short* __restrict__ qo, unsigned short* __restrict__ ko,
    float* __restrict__ den, int N)
{
    __shared__ unsigned short WtL[NCOL * WT_STRIDE];  // 36.9 KB
    __shared__ float bL[NCOL];                        // 1 KB
    const int tid = threadIdx.x;

    for (int i = tid; i < NFEAT * NCOL; i += 256) {
        const int kk = i >> 8, c = i & 255;
        WtL[c * WT_STRIDE + kk] = f2bf(W[i]);
    }
    bL[tid] = b[tid];

    // zero denom: 391 blocks * 256 = 100096 >= 2N
    const int t = blockIdx.x * 256 + tid;
    if (t < 2 * N) den[t] = 0.f;

    const int lane = tid & 63;
    const int wv   = tid >> 6;
    const int l15  = lane & 15;
    const int quad = lane >> 4;
    const int base = blockIdx.x * 128 + wv * 32;
    __syncthreads();

    if (base >= N) return;

    bf16x8 afrag[2][2];
#pragma unroll
    for (int s = 0; s < 2; ++s) {
        int m = base + s * 16 + l15;
        if (m >= N) m = N - 1;                      // clamp (stores guarded)
        const float* xp = x + (size_t)m * NFEAT + quad * 8;
#pragma unroll
        for (int ks = 0; ks < 2; ++ks) {
            float4 a0 = *(const float4*)(xp + ks * 32);
            float4 a1 = *(const float4*)(xp + ks * 32 + 4);
            bf16x8 f;
            f[0] = f2bf(a0.x); f[1] = f2bf(a0.y); f[2] = f2bf(a0.z); f[3] = f2bf(a0.w);
            f[4] = f2bf(a1.x); f[5] = f2bf(a1.y); f[6] = f2bf(a1.z); f[7] = f2bf(a1.w);
            afrag[s][ks] = f;
        }
    }

#pragma unroll 4
    for (int ct = 0; ct < 16; ++ct) {
        const int c = ct * 16 + l15;
        bf16x8 b0 = *(const bf16x8*)(WtL + (size_t)c * WT_STRIDE + quad * 8);
        bf16x8 b1 = *(const bf16x8*)(WtL + (size_t)c * WT_STRIDE + 32 + quad * 8);
        const float bias = bL[c];
        const int h   = c >> 7;
        const int isk = (c >> 6) & 1;
        const int f0  = c & 63;
        unsigned short* dst = isk ? ko : qo;
#pragma unroll
        for (int s = 0; s < 2; ++s) {
            f32x4 acc = {0.f, 0.f, 0.f, 0.f};
            acc = __builtin_amdgcn_mfma_f32_16x16x32_bf16(afrag[s][0], b0, acc, 0, 0, 0);
            acc = __builtin_amdgcn_mfma_f32_16x16x32_bf16(afrag[s][1], b1, acc, 0, 0, 0);
#pragma unroll
            for (int r = 0; r < 4; ++r) {
                const int m = base + s * 16 + quad * 4 + r;
                if (m < N)
                    dst[(size_t)m * 128 + h * 64 + f0] = f2bf(acc[r] + bias);
            }
        }
    }
}

// ---------------- Kernel 2: scores -> exp -> segment-sum, 4 edges per 16-lane group ----------------
// 16 lanes/edge; q[row],k[col] are 128 bf16 = 256B -> one uint4 (8 bf16) per lane.
// 4 edges per group: 8 gathers in flight (MLP; R6 showed rate-bound, but this also
// amortizes index loads). Lanes 0-7: head 0, lanes 8-15: head 1.
__global__ __launch_bounds__(256) void edge_scores_exp(
    const unsigned short* __restrict__ q, const unsigned short* __restrict__ k,
    const int* __restrict__ ei, float* __restrict__ ex_out,
    float* __restrict__ denom, int E)
{
    const int grp  = (int)((blockIdx.x * 256 + threadIdx.x) >> 4);
    const int lane = threadIdx.x & 15;
    const int g0   = grp * 4;
    if (g0 >= E) return;

    int v = 0;
    if (lane < 4)      v = ei[g0 + lane];
    else if (lane < 8) v = ei[E + g0 + (lane - 4)];
    int rows[4], cols[4];
#pragma unroll
    for (int i = 0; i < 4; ++i) {
        rows[i] = __shfl(v, i, 16);
        cols[i] = __shfl(v, 4 + i, 16);
    }

    uint4 qa[4], ka[4];
#pragma unroll
    for (int i = 0; i < 4; ++i) {
        qa[i] = ((const uint4*)(q + (size_t)rows[i] * 128))[lane];
        ka[i] = ((const uint4*)(k + (size_t)cols[i] * 128))[lane];
    }

#pragma unroll
    for (int i = 0; i < 4; ++i) {
        float p = dot_bf16x2(qa[i].x, ka[i].x) + dot_bf16x2(qa[i].y, ka[i].y)
                + dot_bf16x2(qa[i].z, ka[i].z) + dot_bf16x2(qa[i].w, ka[i].w);
        p += __shfl_xor(p, 1);
        p += __shfl_xor(p, 2);
        p += __shfl_xor(p, 4);
        if ((lane & 7) == 0 && g0 + i < E) {
            const int h  = lane >> 3;
            const float e = __expf(p);
            ex_out[(size_t)(g0 + i) * 2 + h] = e;
            atomicAdd(&denom[(size_t)rows[i] * 2 + h], e);
        }
    }
}

// ---------------- Kernel 3: normalize + mean over heads ----------------
__global__ __launch_bounds__(256) void edge_out_k(
    const int* __restrict__ ei, const float* __restrict__ ex,
    const float* __restrict__ denom, float* __restrict__ out, int E)
{
    const int e = blockIdx.x * 256 + threadIdx.x;
    if (e >= E) return;
    const int row = ei[e];
    const float2 exv = *(const float2*)&ex[(size_t)e * 2];
    const float2 dv  = *(const float2*)&denom[(size_t)row * 2];
    out[e] = 0.5f * (exv.x / dv.x + exv.y / dv.y);
}

extern "C" void kernel_launch(void* const* d_in, const int* in_sizes, int n_in,
                              void* d_out, int out_size, void* d_ws, size_t ws_size,
                              hipStream_t stream)
{
    const float* x   = (const float*)d_in[0];
    const float* W   = (const float*)d_in[1];
    const float* b   = (const float*)d_in[2];
    const int*   ei  = (const int*)d_in[3];
    float*       out = (float*)d_out;

    const int N = in_sizes[0] / NFEAT;     // 50000
    const int E = in_sizes[3] / 2;         // 800000

    char* ws = (char*)d_ws;
    size_t off = 0;
    auto alloc = [&](size_t bytes) { void* p = ws + off; off += (bytes + 255) & ~(size_t)255; return p; };
    unsigned short* q_ws  = (unsigned short*)alloc((size_t)N * 128 * 2);        // 12.8 MB
    unsigned short* k_ws  = (unsigned short*)alloc((size_t)N * 128 * 2);        // 12.8 MB
    float*          ex_ws = (float*)alloc((size_t)E * 2 * sizeof(float));       // 6.4 MB
    float*          den_ws= (float*)alloc((size_t)N * 2 * sizeof(float));       // 0.4 MB
    (void)ws_size;

    gemm_qk_mfma<<<(N + 127) / 128, 256, 0, stream>>>(x, W, b, q_ws, k_ws, den_ws, N);
    edge_scores_exp<<<((size_t)(E + 3) / 4 * 16 + 255) / 256, 256, 0, stream>>>(q_ws, k_ws, ei, ex_ws, den_ws, E);
    edge_out_k<<<(E + 255) / 256, 256, 0, stream>>>(ei, ex_ws, den_ws, out, E);
}